// Round 3
// baseline (475.702 us; speedup 1.0000x reference)
//
#include <hip/hip_runtime.h>
#include <math.h>

// Problem: N=8, C=1, H=W=512 fp32. 16 images (8 sigmoid + 8 target) skeletonized.
#define IMG   512
#define NSAMP 8
#define NIMG  16
#define PS    (IMG * IMG)

__device__ __forceinline__ float sigm(float x) { return 1.0f / (1.0f + expf(-x)); }

// ---- cross-lane shift by 1 at VALU rate (DPP). Stencils are L/R symmetric,
// so shift direction need not be disambiguated. Invalid lanes -> 0 (garbage
// contained in the (C+1)-lane column halo).
__device__ __forceinline__ float dpp_a(float x) {
#if __has_builtin(__builtin_amdgcn_update_dpp)
    return __int_as_float(__builtin_amdgcn_update_dpp(0, __float_as_int(x),
                                                      0x130, 0xF, 0xF, true)); // WAVE_SHL1
#else
    return __shfl_down(x, 1, 64);
#endif
}
__device__ __forceinline__ float dpp_b(float x) {
#if __has_builtin(__builtin_amdgcn_update_dpp)
    return __int_as_float(__builtin_amdgcn_update_dpp(0, __float_as_int(x),
                                                      0x138, 0xF, 0xF, true)); // WAVE_SHR1
#else
    return __shfl_up(x, 1, 64);
#endif
}

// ---- prep: X[0:n]=sigmoid(logits), X[n:2n]=target, S=0 ----
__global__ __launch_bounds__(256) void prep_kernel(const float4* __restrict__ lg,
                                                   const float4* __restrict__ tg,
                                                   float4* __restrict__ X,
                                                   float4* __restrict__ S, int n4)
{
    int i = blockIdx.x * 256 + threadIdx.x;
    if (i < n4) {
        float4 L = lg[i];
        X[i]      = make_float4(sigm(L.x), sigm(L.y), sigm(L.z), sigm(L.w));
        X[i + n4] = tg[i];
        float4 z = make_float4(0.f, 0.f, 0.f, 0.f);
        S[i]      = z;
        S[i + n4] = z;
    }
}

// ---- register line-pipeline: C fused levels, no LDS ----
// Per level l (rows indexed by step t):
//   x_{l+1}[t-l-1] = erode(x_l)      (cross min; A=x_l[t-l-2], B=x_l[t-l-1], C=x_l[t-l])
//   hm[t-l-1]      = rowmax3(x_{l+1})
//   dil[t-l-2]     = max(HMA,HMB,hm) ; delta_l[t-l-2] = relu(x_l[t-l-2] - dil) = relu(A - dil)
//   SK[l] (skel row t-l-2) += relu(delta - SK*delta); SK shifts 1 slot/step.
template<int C, bool ER, bool EC>
__device__ __forceinline__ void pipe_run(const float* __restrict__ xg,
                                         float* __restrict__ xo,
                                         float* __restrict__ Sg,
                                         int R0, int R1, int gcol, bool colOK, bool owned)
{
    const float INF = __builtin_inff();
    float A[C], B[C], HMA[C], HMB[C], SK[C];
    #pragma unroll
    for (int l = 0; l < C; ++l) {
        A[l] = INF; B[l] = INF; HMA[l] = -INF; HMB[l] = -INF; SK[l] = 0.f;
    }
    const int t0 = R0 - C - 1, t1 = R1 + C;

    auto xload = [&](int r) -> float {
        float v = INF;
        if ((unsigned)r < (unsigned)IMG && colOK) v = xg[r * IMG + gcol];
        return v;
    };
    auto sload = [&](int r) -> float {
        float v = 0.f;
        if ((unsigned)r < (unsigned)IMG && colOK) v = Sg[r * IMG + gcol];
        return v;
    };

    // 2-step prefetch on both streaming loads
    float X0a = xload(t0), X0b = xload(t0 + 1);
    float SNa = sload(t0 - 1), SNb = sload(t0);

    for (int t = t0; t <= t1; ++t) {
        float Cin = X0a; X0a = X0b; X0b = xload(t + 2);

        #pragma unroll
        for (int l = 0; l < C; ++l) {
            float Acur = A[l], Bcur = B[l];
            // erode -> x_{l+1}[t-l-1]
            float e = fminf(fminf(Acur, Cin), Bcur);
            e = fminf(e, dpp_a(Bcur));
            e = fminf(e, dpp_b(Bcur));
            if (ER) e = ((unsigned)(t - l - 1) < (unsigned)IMG) ? e : INF;   // uniform
            float eraw = e, xd = eraw;
            if (EC) {                       // per-lane column-boundary forcing
                e  = colOK ? eraw :  INF;   // as erode input of next level
                xd = colOK ? eraw : -INF;   // as dilate input
            }
            float hm = fmaxf(xd, dpp_a(xd));
            hm = fmaxf(hm, dpp_b(xd));
            if (ER) hm = ((unsigned)(t - l - 1) < (unsigned)IMG) ? hm : -INF; // uniform
            float dil = fmaxf(fmaxf(HMA[l], HMB[l]), hm);
            float delta = fmaxf(Acur - dil, 0.f);
            float skl = SK[l];
            SK[l] = skl + fmaxf(delta - skl * delta, 0.f);
            // rotate windows
            A[l] = Bcur; B[l] = Cin;
            HMA[l] = HMB[l]; HMB[l] = hm;
            Cin = e;                        // next level's fresh row
        }

        // stores: x_C row t-C, skel row t-C-1 (only owned lanes, only band rows)
        int rx = t - C;
        if ((unsigned)(rx - R0) < (unsigned)(R1 - R0)) {
            if (owned) xo[rx * IMG + gcol] = Cin;
        }
        int rs = rx - 1;
        if ((unsigned)(rs - R0) < (unsigned)(R1 - R0)) {
            if (owned) Sg[rs * IMG + gcol] = SK[C - 1];
        }
        // shift skel pipeline, insert prefetched skel[t-1]
        #pragma unroll
        for (int j = C - 1; j >= 1; --j) SK[j] = SK[j - 1];
        SK[0] = SNa; SNa = SNb; SNb = sload(t + 1);
    }
}

template<int C>
__global__ __launch_bounds__(256) void fused_pipe(const float* __restrict__ xin,
                                                  float* __restrict__ xout,
                                                  float* __restrict__ S)
{
    constexpr int OW = 64 - 2 * (C + 1);                 // owned cols per wave
    constexpr int NSTRIP = (IMG + OW - 1) / OW;          // 13 for C=10,11
    constexpr int NBANDS = 8, BH = IMG / NBANDS;
    const int lane = threadIdx.x & 63;
    const int task = blockIdx.x * 4 + (threadIdx.x >> 6);
    const int strip = task % NSTRIP;
    const int rem = task / NSTRIP;
    const int band = rem % NBANDS;
    const int img = rem / NBANDS;
    const int R0 = band * BH, R1 = R0 + BH;
    const int gcol = strip * OW - (C + 1) + lane;
    const bool colOK = (unsigned)gcol < (unsigned)IMG;
    const bool owned = (lane >= C + 1) && (lane < C + 1 + OW) && colOK;
    const float* xg = xin + (size_t)img * PS;
    float* xo = xout + (size_t)img * PS;
    float* Sg = S + (size_t)img * PS;
    const bool erow = (band == 0) || (band == NBANDS - 1);
    const bool ecol = (strip == 0) || (strip * OW - (C + 1) + 63 >= IMG);

    if (erow) {
        if (ecol) pipe_run<C, true , true >(xg, xo, Sg, R0, R1, gcol, colOK, owned);
        else      pipe_run<C, true , false>(xg, xo, Sg, R0, R1, gcol, colOK, owned);
    } else {
        if (ecol) pipe_run<C, false, true >(xg, xo, Sg, R0, R1, gcol, colOK, owned);
        else      pipe_run<C, false, false>(xg, xo, Sg, R0, R1, gcol, colOK, owned);
    }
}

// ---- reduction: per-block partials, no global atomics ----
__global__ __launch_bounds__(256) void reduce_kernel(const float* __restrict__ logits,
                                                     const float* __restrict__ target,
                                                     const float* __restrict__ S,
                                                     float* __restrict__ partial)
{
    const int sample = blockIdx.y;
    const size_t base = (size_t)sample * PS;
    const float4* p4  = (const float4*)(logits + base);
    const float4* t4  = (const float4*)(target + base);
    const float4* sp4 = (const float4*)(S + base);
    const float4* sl4 = (const float4*)(S + (size_t)NSAMP * PS + base);
    float v[7] = {0.f, 0.f, 0.f, 0.f, 0.f, 0.f, 0.f};
    const int n4 = PS / 4;
    for (int i = blockIdx.x * 256 + threadIdx.x; i < n4; i += 32 * 256) {
        float4 L = p4[i], Tt = t4[i], SP = sp4[i], SL = sl4[i];
        float p;
        p = sigm(L.x); v[0] += SP.x * Tt.x; v[1] += SP.x; v[2] += SL.x * p; v[3] += SL.x; v[4] += p * Tt.x; v[5] += p; v[6] += Tt.x;
        p = sigm(L.y); v[0] += SP.y * Tt.y; v[1] += SP.y; v[2] += SL.y * p; v[3] += SL.y; v[4] += p * Tt.y; v[5] += p; v[6] += Tt.y;
        p = sigm(L.z); v[0] += SP.z * Tt.z; v[1] += SP.z; v[2] += SL.z * p; v[3] += SL.z; v[4] += p * Tt.z; v[5] += p; v[6] += Tt.z;
        p = sigm(L.w); v[0] += SP.w * Tt.w; v[1] += SP.w; v[2] += SL.w * p; v[3] += SL.w; v[4] += p * Tt.w; v[5] += p; v[6] += Tt.w;
    }
    #pragma unroll
    for (int off = 32; off > 0; off >>= 1)
        #pragma unroll
        for (int q = 0; q < 7; ++q) v[q] += __shfl_down(v[q], off);
    __shared__ float wred[4][7];
    int lane = threadIdx.x & 63, w = threadIdx.x >> 6;
    if (lane == 0)
        #pragma unroll
        for (int q = 0; q < 7; ++q) wred[w][q] = v[q];
    __syncthreads();
    if (threadIdx.x == 0) {
        #pragma unroll
        for (int q = 0; q < 7; ++q)
            partial[(sample * 32 + blockIdx.x) * 7 + q] =
                wred[0][q] + wred[1][q] + wred[2][q] + wred[3][q];
    }
}

__global__ __launch_bounds__(256) void final_kernel(const float* __restrict__ partial,
                                                    float* __restrict__ out)
{
    const int t = threadIdx.x;
    const int sample = t >> 5, part = t & 31;
    float v[7];
    #pragma unroll
    for (int q = 0; q < 7; ++q) v[q] = partial[(sample * 32 + part) * 7 + q];
    #pragma unroll
    for (int off = 16; off > 0; off >>= 1)
        #pragma unroll
        for (int q = 0; q < 7; ++q) v[q] += __shfl_down(v[q], off, 32);
    __shared__ float acc[NSAMP][7];
    if (part == 0)
        #pragma unroll
        for (int q = 0; q < 7; ++q) acc[sample][q] = v[q];
    __syncthreads();
    if (t == 0) {
        float cl = 0.f, dice = 0.f;
        for (int n = 0; n < NSAMP; n++) {
            float A = acc[n][0], Bv = acc[n][1], Cc = acc[n][2], D = acc[n][3];
            float E = acc[n][4], F = acc[n][5], G = acc[n][6];
            float tprec = (A + 1.0f) / (Bv + 1.0f);
            float tsens = (Cc + 1.0f) / (D + 1.0f);
            cl   += 1.0f - 2.0f * tprec * tsens / (tprec + tsens);
            dice += 1.0f - 2.0f * (E + 1.0f) / (F + G + 1.0f);
        }
        out[0] = 0.7f * (dice / NSAMP) + 0.3f * (cl / NSAMP);
    }
}

extern "C" void kernel_launch(void* const* d_in, const int* in_sizes, int n_in,
                              void* d_out, int out_size, void* d_ws, size_t ws_size,
                              hipStream_t stream)
{
    const float* logits = (const float*)d_in[0];
    const float* target = (const float*)d_in[1];
    float* out = (float*)d_out;

    const size_t NTOT = (size_t)NIMG * PS;
    float* Xa = (float*)d_ws;                       // Xa | Xb | S | partial
    float* Xb = Xa + NTOT;
    float* S  = Xb + NTOT;
    float* partial = S + NTOT;                      // 256*7 floats

    const int n4 = (NSAMP * PS) / 4;
    prep_kernel<<<n4 / 256, 256, 0, stream>>>((const float4*)logits, (const float4*)target,
                                              (float4*)Xa, (float4*)S, n4);

    // tasks = NSTRIP(13) * NBANDS(8) * NIMG(16) = 1664 waves -> 416 blocks of 4 waves
    const int blocks = 13 * 8 * NIMG / 4;
    // 51 pipeline levels total: 11 + 4*10
    fused_pipe<11><<<blocks, 256, 0, stream>>>(Xa, Xb, S);
    fused_pipe<10><<<blocks, 256, 0, stream>>>(Xb, Xa, S);
    fused_pipe<10><<<blocks, 256, 0, stream>>>(Xa, Xb, S);
    fused_pipe<10><<<blocks, 256, 0, stream>>>(Xb, Xa, S);
    fused_pipe<10><<<blocks, 256, 0, stream>>>(Xa, Xb, S);

    reduce_kernel<<<dim3(32, NSAMP), 256, 0, stream>>>(logits, target, S, partial);
    final_kernel<<<1, 256, 0, stream>>>(partial, out);
}

// Round 4
// 343.067 us; speedup vs baseline: 1.3866x; 1.3866x over previous
//
#include <hip/hip_runtime.h>
#include <math.h>

// Problem: N=8, C=1, H=W=512 fp32. 16 images (8 sigmoid + 8 target) skeletonized.
#define IMG   512
#define NSAMP 8
#define NIMG  16
#define PS    (IMG * IMG)

#define NBANDS 16
#define BH     (IMG / NBANDS)   // 32

__device__ __forceinline__ float sigm(float x) { return 1.0f / (1.0f + expf(-x)); }

// ---- cross-lane shift by 1 at VALU rate (DPP). Stencils are L/R symmetric,
// so shift direction need not be disambiguated. Invalid lanes -> 0 (garbage
// contained in the (C+1)-lane column halo).
__device__ __forceinline__ float dpp_a(float x) {
#if __has_builtin(__builtin_amdgcn_update_dpp)
    return __int_as_float(__builtin_amdgcn_update_dpp(0, __float_as_int(x),
                                                      0x130, 0xF, 0xF, true)); // WAVE_SHL1
#else
    return __shfl_down(x, 1, 64);
#endif
}
__device__ __forceinline__ float dpp_b(float x) {
#if __has_builtin(__builtin_amdgcn_update_dpp)
    return __int_as_float(__builtin_amdgcn_update_dpp(0, __float_as_int(x),
                                                      0x138, 0xF, 0xF, true)); // WAVE_SHR1
#else
    return __shfl_up(x, 1, 64);
#endif
}

// ---- prep: X[0:n]=sigmoid(logits), X[n:2n]=target  (S not touched: first
// fused launch runs INIT=true and neither reads nor needs zeroed S) ----
__global__ __launch_bounds__(256) void prep_kernel(const float4* __restrict__ lg,
                                                   const float4* __restrict__ tg,
                                                   float4* __restrict__ X, int n4)
{
    int i = blockIdx.x * 256 + threadIdx.x;
    if (i < n4) {
        float4 L = lg[i];
        X[i]      = make_float4(sigm(L.x), sigm(L.y), sigm(L.z), sigm(L.w));
        X[i + n4] = tg[i];
    }
}

// ---- register line-pipeline: C fused levels, no LDS ----
// Per level l (rows indexed by step t):
//   x_{l+1}[t-l-1] = erode(x_l)      (cross min; A=x_l[t-l-2], B=x_l[t-l-1], C=x_l[t-l])
//   hm[t-l-1]      = rowmax3(x_{l+1})
//   dil[t-l-2]     = max(HMA,HMB,hm) ; delta_l[t-l-2] = relu(A - dil)
//   SK[l] (skel row t-l-2) += relu(delta - SK*delta); SK shifts 1 slot/step.
// Templates: ER = band touches image top/bottom (row guards needed);
//            EC = strip touches image left/right (per-lane col guards needed);
//            INIT = S is implicitly zero (skip S loads).
template<int C, bool ER, bool EC, bool INIT>
__device__ __forceinline__ void pipe_run(const float* __restrict__ xg,
                                         float* __restrict__ xo,
                                         float* __restrict__ Sg,
                                         int R0, int R1, int gcol, bool colOK, bool owned)
{
    const float INF = __builtin_inff();
    float A[C], B[C], HMA[C], HMB[C], SK[C];
    #pragma unroll
    for (int l = 0; l < C; ++l) {
        A[l] = INF; B[l] = INF; HMA[l] = -INF; HMB[l] = -INF; SK[l] = 0.f;
    }
    const int t0 = R0 - C - 1, t1 = R1 + C;

    auto xload = [&](int r) -> float {
        if (ER || EC) {
            bool ok = true;
            if (ER) ok = ok && ((unsigned)r < (unsigned)IMG);
            if (EC) ok = ok && colOK;
            float v = INF;
            if (ok) v = xg[r * IMG + gcol];
            return v;
        }
        return xg[r * IMG + gcol];    // interior: rows/cols provably in-bounds
    };
    auto sload = [&](int r) -> float {
        if (INIT) return 0.f;
        if (ER || EC) {
            bool ok = true;
            if (ER) ok = ok && ((unsigned)r < (unsigned)IMG);
            if (EC) ok = ok && colOK;
            float v = 0.f;
            if (ok) v = Sg[r * IMG + gcol];
            return v;
        }
        return Sg[r * IMG + gcol];
    };

    // 2-step prefetch on both streaming loads
    float X0a = xload(t0), X0b = xload(t0 + 1);
    float SNa = sload(t0 - 1), SNb = sload(t0);

    #pragma unroll 2
    for (int t = t0; t <= t1; ++t) {
        float Cin = X0a; X0a = X0b; X0b = xload(t + 2);

        #pragma unroll
        for (int l = 0; l < C; ++l) {
            float Acur = A[l], Bcur = B[l];
            // erode -> x_{l+1}[t-l-1]
            float e = fminf(fminf(Acur, Cin), Bcur);
            e = fminf(e, dpp_a(Bcur));
            e = fminf(e, dpp_b(Bcur));
            if (ER) e = ((unsigned)(t - l - 1) < (unsigned)IMG) ? e : INF;   // uniform
            float eraw = e, xd = eraw;
            if (EC) {                       // per-lane column-boundary forcing
                e  = colOK ? eraw :  INF;   // as erode input of next level
                xd = colOK ? eraw : -INF;   // as dilate input
            }
            float hm = fmaxf(xd, dpp_a(xd));
            hm = fmaxf(hm, dpp_b(xd));
            if (ER) hm = ((unsigned)(t - l - 1) < (unsigned)IMG) ? hm : -INF; // uniform
            float dil = fmaxf(fmaxf(HMA[l], HMB[l]), hm);
            float delta = fmaxf(Acur - dil, 0.f);
            float skl = SK[l];
            SK[l] = skl + fmaxf(delta - skl * delta, 0.f);
            // rotate windows
            A[l] = Bcur; B[l] = Cin;
            HMA[l] = HMB[l]; HMB[l] = hm;
            Cin = e;                        // next level's fresh row
        }

        // stores: x_C row t-C, skel row t-C-1 (only owned lanes, only band rows)
        int rx = t - C;
        if ((unsigned)(rx - R0) < (unsigned)(R1 - R0)) {
            if (owned) xo[rx * IMG + gcol] = Cin;
        }
        int rs = rx - 1;
        if ((unsigned)(rs - R0) < (unsigned)(R1 - R0)) {
            if (owned) Sg[rs * IMG + gcol] = SK[C - 1];
        }
        // shift skel pipeline, insert prefetched skel[t-1]
        #pragma unroll
        for (int j = C - 1; j >= 1; --j) SK[j] = SK[j - 1];
        SK[0] = SNa; SNa = SNb; SNb = sload(t + 1);
    }
}

template<int C, bool INIT>
__global__ __launch_bounds__(256) void fused_pipe(const float* __restrict__ xin,
                                                  float* __restrict__ xout,
                                                  float* __restrict__ S)
{
    constexpr int OW = 64 - 2 * (C + 1);                 // owned cols per wave
    constexpr int NSTRIP = (IMG + OW - 1) / OW;          // 10 (C=5), 11 (C=6)
    const int lane = threadIdx.x & 63;
    const int task = blockIdx.x * 4 + (threadIdx.x >> 6);
    const int strip = task % NSTRIP;
    const int rem = task / NSTRIP;
    const int band = rem % NBANDS;
    const int img = rem / NBANDS;
    const int R0 = band * BH, R1 = R0 + BH;
    const int gcol = strip * OW - (C + 1) + lane;
    const bool colOK = (unsigned)gcol < (unsigned)IMG;
    const bool owned = (lane >= C + 1) && (lane < C + 1 + OW) && colOK;
    const float* xg = xin + (size_t)img * PS;
    float* xo = xout + (size_t)img * PS;
    float* Sg = S + (size_t)img * PS;
    const bool erow = (band == 0) || (band == NBANDS - 1);
    const bool ecol = (strip == 0) || (strip * OW - (C + 1) + 63 >= IMG);

    if (erow) {
        if (ecol) pipe_run<C, true , true , INIT>(xg, xo, Sg, R0, R1, gcol, colOK, owned);
        else      pipe_run<C, true , false, INIT>(xg, xo, Sg, R0, R1, gcol, colOK, owned);
    } else {
        if (ecol) pipe_run<C, false, true , INIT>(xg, xo, Sg, R0, R1, gcol, colOK, owned);
        else      pipe_run<C, false, false, INIT>(xg, xo, Sg, R0, R1, gcol, colOK, owned);
    }
}

// ---- reduction: per-block partials, no global atomics ----
__global__ __launch_bounds__(256) void reduce_kernel(const float* __restrict__ logits,
                                                     const float* __restrict__ target,
                                                     const float* __restrict__ S,
                                                     float* __restrict__ partial)
{
    const int sample = blockIdx.y;
    const size_t base = (size_t)sample * PS;
    const float4* p4  = (const float4*)(logits + base);
    const float4* t4  = (const float4*)(target + base);
    const float4* sp4 = (const float4*)(S + base);
    const float4* sl4 = (const float4*)(S + (size_t)NSAMP * PS + base);
    float v[7] = {0.f, 0.f, 0.f, 0.f, 0.f, 0.f, 0.f};
    const int n4 = PS / 4;
    for (int i = blockIdx.x * 256 + threadIdx.x; i < n4; i += 32 * 256) {
        float4 L = p4[i], Tt = t4[i], SP = sp4[i], SL = sl4[i];
        float p;
        p = sigm(L.x); v[0] += SP.x * Tt.x; v[1] += SP.x; v[2] += SL.x * p; v[3] += SL.x; v[4] += p * Tt.x; v[5] += p; v[6] += Tt.x;
        p = sigm(L.y); v[0] += SP.y * Tt.y; v[1] += SP.y; v[2] += SL.y * p; v[3] += SL.y; v[4] += p * Tt.y; v[5] += p; v[6] += Tt.y;
        p = sigm(L.z); v[0] += SP.z * Tt.z; v[1] += SP.z; v[2] += SL.z * p; v[3] += SL.z; v[4] += p * Tt.z; v[5] += p; v[6] += Tt.z;
        p = sigm(L.w); v[0] += SP.w * Tt.w; v[1] += SP.w; v[2] += SL.w * p; v[3] += SL.w; v[4] += p * Tt.w; v[5] += p; v[6] += Tt.w;
    }
    #pragma unroll
    for (int off = 32; off > 0; off >>= 1)
        #pragma unroll
        for (int q = 0; q < 7; ++q) v[q] += __shfl_down(v[q], off);
    __shared__ float wred[4][7];
    int lane = threadIdx.x & 63, w = threadIdx.x >> 6;
    if (lane == 0)
        #pragma unroll
        for (int q = 0; q < 7; ++q) wred[w][q] = v[q];
    __syncthreads();
    if (threadIdx.x == 0) {
        #pragma unroll
        for (int q = 0; q < 7; ++q)
            partial[(sample * 32 + blockIdx.x) * 7 + q] =
                wred[0][q] + wred[1][q] + wred[2][q] + wred[3][q];
    }
}

__global__ __launch_bounds__(256) void final_kernel(const float* __restrict__ partial,
                                                    float* __restrict__ out)
{
    const int t = threadIdx.x;
    const int sample = t >> 5, part = t & 31;
    float v[7];
    #pragma unroll
    for (int q = 0; q < 7; ++q) v[q] = partial[(sample * 32 + part) * 7 + q];
    #pragma unroll
    for (int off = 16; off > 0; off >>= 1)
        #pragma unroll
        for (int q = 0; q < 7; ++q) v[q] += __shfl_down(v[q], off, 32);
    __shared__ float acc[NSAMP][7];
    if (part == 0)
        #pragma unroll
        for (int q = 0; q < 7; ++q) acc[sample][q] = v[q];
    __syncthreads();
    if (t == 0) {
        float cl = 0.f, dice = 0.f;
        for (int n = 0; n < NSAMP; n++) {
            float A = acc[n][0], Bv = acc[n][1], Cc = acc[n][2], D = acc[n][3];
            float E = acc[n][4], F = acc[n][5], G = acc[n][6];
            float tprec = (A + 1.0f) / (Bv + 1.0f);
            float tsens = (Cc + 1.0f) / (D + 1.0f);
            cl   += 1.0f - 2.0f * tprec * tsens / (tprec + tsens);
            dice += 1.0f - 2.0f * (E + 1.0f) / (F + G + 1.0f);
        }
        out[0] = 0.7f * (dice / NSAMP) + 0.3f * (cl / NSAMP);
    }
}

extern "C" void kernel_launch(void* const* d_in, const int* in_sizes, int n_in,
                              void* d_out, int out_size, void* d_ws, size_t ws_size,
                              hipStream_t stream)
{
    const float* logits = (const float*)d_in[0];
    const float* target = (const float*)d_in[1];
    float* out = (float*)d_out;

    const size_t NTOT = (size_t)NIMG * PS;
    float* Xa = (float*)d_ws;                       // Xa | Xb | S | partial
    float* Xb = Xa + NTOT;
    float* S  = Xb + NTOT;
    float* partial = S + NTOT;                      // 256*7 floats

    const int n4 = (NSAMP * PS) / 4;
    prep_kernel<<<n4 / 256, 256, 0, stream>>>((const float4*)logits, (const float4*)target,
                                              (float4*)Xa, n4);

    // 51 levels = 6 + 9*5.  tasks = NSTRIP*16*16; blocks = tasks/4.
    fused_pipe<6, true ><<<11 * 64, 256, 0, stream>>>(Xa, Xb, S);   // 2816 waves
    fused_pipe<5, false><<<10 * 64, 256, 0, stream>>>(Xb, Xa, S);   // 2560 waves
    fused_pipe<5, false><<<10 * 64, 256, 0, stream>>>(Xa, Xb, S);
    fused_pipe<5, false><<<10 * 64, 256, 0, stream>>>(Xb, Xa, S);
    fused_pipe<5, false><<<10 * 64, 256, 0, stream>>>(Xa, Xb, S);
    fused_pipe<5, false><<<10 * 64, 256, 0, stream>>>(Xb, Xa, S);
    fused_pipe<5, false><<<10 * 64, 256, 0, stream>>>(Xa, Xb, S);
    fused_pipe<5, false><<<10 * 64, 256, 0, stream>>>(Xb, Xa, S);
    fused_pipe<5, false><<<10 * 64, 256, 0, stream>>>(Xa, Xb, S);
    fused_pipe<5, false><<<10 * 64, 256, 0, stream>>>(Xb, Xa, S);

    reduce_kernel<<<dim3(32, NSAMP), 256, 0, stream>>>(logits, target, S, partial);
    final_kernel<<<1, 256, 0, stream>>>(partial, out);
}